// Round 2
// baseline (440.796 us; speedup 1.0000x reference)
//
#include <hip/hip_runtime.h>

// DCNv2 forward, fp32. Fixed problem size from the reference:
#define N_    4
#define C_    64
#define H_    128
#define W_    128
#define KH_   3
#define KW_   3
#define K_    9       // KH*KW
#define COUT_ 64
#define HW_   (H_ * W_)   // 16384

#define SPLIT_   4                  // c-reduction split factor
#define CSUB_    (C_ / SPLIT_)      // 16 input channels per thread
#define PIXB_    64                 // pixels per block

// ---------------------------------------------------------------------------
// Prologue: transpose weight[o][c][k] (Cout,C,K) -> wT[(c*K+k)*COUT + o]
// so the hot loop's 64 uniform weight reads are contiguous scalar loads.
// ---------------------------------------------------------------------------
__global__ void transpose_weight(const float* __restrict__ w,
                                 float* __restrict__ wT) {
    int tid = blockIdx.x * blockDim.x + threadIdx.x;   // 0 .. 36863
    if (tid >= COUT_ * C_ * K_) return;
    int o  = tid & (COUT_ - 1);   // fastest: output channel
    int ck = tid >> 6;            // c*K + k
    wT[tid] = w[o * (C_ * K_) + ck];
}

// ---------------------------------------------------------------------------
// Main kernel: block = 64 pixels x 4 c-parts (256 threads).
// Each thread: gathers its 16 input channels for its pixel, accumulates all
// 64 output channels in registers; LDS reduction across the 4 parts.
// x-gather load count is IDENTICAL to the unsplit kernel (no replication);
// only offset/mask loads are read 4x (L1-resident, negligible).
// ---------------------------------------------------------------------------
template <bool TW>
__global__ __launch_bounds__(256, 4) void dcn_fwd(
    const float* __restrict__ x,       // (N, C, H, W)
    const float* __restrict__ offset,  // (N, 2*K, H, W)  ch = 2k (+0=y, +1=x)
    const float* __restrict__ mask,    // (N, K, H, W)
    const float* __restrict__ wptr,    // TW ? wT[ck*64+o] : weight[o*576+ck]
    const float* __restrict__ bias,    // (Cout,)
    float* __restrict__ out)           // (N, Cout, H, W)
{
    const int part = threadIdx.x >> 6;        // 0..3  (one wave per part)
    const int pixl = threadIdx.x & 63;        // 0..63 (consecutive lanes = consecutive wo)
    const int pix_base = blockIdx.x * PIXB_;  // 64 | HW_, so block never crosses images
    const int n   = pix_base >> 14;           // / HW_
    const int hwb = pix_base & (HW_ - 1);
    const int hw  = hwb + pixl;
    const int ho  = hw >> 7;                  // / W_
    const int wo  = hw & (W_ - 1);

    float acc[COUT_];
#pragma unroll
    for (int o = 0; o < COUT_; ++o) acc[o] = 0.f;

    const float* xn   = x      + n * (C_ * HW_);
    const float* offn = offset + n * (2 * K_ * HW_) + hw;
    const float* mn   = mask   + n * (K_ * HW_)     + hw;
    const int c0 = part * CSUB_;

    for (int k = 0; k < K_; ++k) {
        const int ky = k / KW_;
        const int kx = k - ky * KW_;

        const float off_y = offn[(2 * k + 0) * HW_];
        const float off_x = offn[(2 * k + 1) * HW_];
        const float m     = mn[k * HW_];

        const float py = (float)(ho - 1 + ky) + off_y;   // stride=1, pad=1, dil=1
        const float px = (float)(wo - 1 + kx) + off_x;

        const float y0f = floorf(py);
        const float x0f = floorf(px);
        const float ly  = py - y0f;
        const float lx  = px - x0f;

        const int y0 = (int)y0f, x0 = (int)x0f;
        const int y1 = y0 + 1,   x1 = x0 + 1;

        const bool vy0 = (y0 >= 0) && (y0 < H_);
        const bool vy1 = (y1 >= 0) && (y1 < H_);
        const bool vx0 = (x0 >= 0) && (x0 < W_);
        const bool vx1 = (x1 >= 0) && (x1 < W_);

        const int cy0 = min(max(y0, 0), H_ - 1);
        const int cy1 = min(max(y1, 0), H_ - 1);
        const int cx0 = min(max(x0, 0), W_ - 1);
        const int cx1 = min(max(x1, 0), W_ - 1);

        const int i00 = cy0 * W_ + cx0;
        const int i01 = cy0 * W_ + cx1;
        const int i10 = cy1 * W_ + cx0;
        const int i11 = cy1 * W_ + cx1;

        // fold validity + mask into the 4 bilinear corner coefficients
        const float f00 = (1.f - ly) * (1.f - lx) * m * ((vy0 && vx0) ? 1.f : 0.f);
        const float f01 = (1.f - ly) * lx         * m * ((vy0 && vx1) ? 1.f : 0.f);
        const float f10 = ly         * (1.f - lx) * m * ((vy1 && vx0) ? 1.f : 0.f);
        const float f11 = ly         * lx         * m * ((vy1 && vx1) ? 1.f : 0.f);

        for (int cc = 0; cc < CSUB_; ++cc) {
            const int c = c0 + cc;
            const float* xc = xn + c * HW_;
            const float val = fmaf(f00, xc[i00],
                             fmaf(f01, xc[i01],
                             fmaf(f10, xc[i10],
                                  f11 * xc[i11])));
            const int ck = c * K_ + k;
            if (TW) {
                const float* wrow = wptr + ck * COUT_;   // contiguous, uniform
#pragma unroll
                for (int o = 0; o < COUT_; ++o)
                    acc[o] = fmaf(wrow[o], val, acc[o]);
            } else {
#pragma unroll
                for (int o = 0; o < COUT_; ++o)
                    acc[o] = fmaf(wptr[o * (C_ * K_) + ck], val, acc[o]);
            }
        }
    }

    // ---- cross-part reduction via LDS, in 2 chunks of 32 output channels ----
    // red[part][pix][j], j padded to 33: lane addr stride 33 -> conflict-free.
    __shared__ float red[SPLIT_][PIXB_][33];
    float* outp = out + n * (COUT_ * HW_) + hwb;   // + o*HW_ + pix

#pragma unroll
    for (int h = 0; h < 2; ++h) {
        if (h) __syncthreads();              // previous chunk's reads done
#pragma unroll
        for (int j = 0; j < 32; ++j)
            red[part][pixl][j] = acc[h * 32 + j];
        __syncthreads();
        // 2048 elements (64 pix x 32 o), 8 per thread, coalesced stores.
#pragma unroll
        for (int i = 0; i < 8; ++i) {
            const int idx = threadIdx.x + 256 * i;   // 0..2047
            const int ol  = idx >> 6;                // 0..31
            const int p   = idx & 63;                // consecutive per lane
            const int o   = h * 32 + ol;
            const float s = red[0][p][ol] + red[1][p][ol]
                          + red[2][p][ol] + red[3][p][ol] + bias[o];
            outp[o * HW_ + p] = s;
        }
    }
}

extern "C" void kernel_launch(void* const* d_in, const int* in_sizes, int n_in,
                              void* d_out, int out_size, void* d_ws, size_t ws_size,
                              hipStream_t stream) {
    const float* x      = (const float*)d_in[0];
    const float* offset = (const float*)d_in[1];
    const float* mask   = (const float*)d_in[2];
    const float* weight = (const float*)d_in[3];
    const float* bias   = (const float*)d_in[4];
    float* out = (float*)d_out;

    const size_t wT_bytes = (size_t)COUT_ * C_ * K_ * sizeof(float);  // 147456

    const int blocks = (N_ * HW_) / PIXB_;    // 1024

    if (ws_size >= wT_bytes) {
        float* wT = (float*)d_ws;
        transpose_weight<<<(COUT_ * C_ * K_ + 255) / 256, 256, 0, stream>>>(weight, wT);
        dcn_fwd<true><<<blocks, 256, 0, stream>>>(x, offset, mask, wT, bias, out);
    } else {
        dcn_fwd<false><<<blocks, 256, 0, stream>>>(x, offset, mask, weight, bias, out);
    }
}

// Round 3
// 293.877 us; speedup vs baseline: 1.4999x; 1.4999x over previous
//
#include <hip/hip_runtime.h>

// DCNv2 forward, fp32. Fixed problem size from the reference:
#define N_    4
#define C_    64
#define H_    128
#define W_    128
#define KH_   3
#define KW_   3
#define K_    9       // KH*KW
#define COUT_ 64
#define HW_   (H_ * W_)   // 16384

#define CT_   8         // input-channel tile: 8 ch x ~6 rows x 128 cols fp32 ~ 24 KB, L1-resident

// ---------------------------------------------------------------------------
// Prologue: transpose weight[o][c][k] (Cout,C,K) -> wT[(c*K+k)*COUT + o]
// so the hot loop's 64 uniform weight reads are contiguous scalar loads.
// ---------------------------------------------------------------------------
__global__ void transpose_weight(const float* __restrict__ w,
                                 float* __restrict__ wT) {
    int tid = blockIdx.x * blockDim.x + threadIdx.x;   // 0 .. 36863
    if (tid >= COUT_ * C_ * K_) return;
    int o  = tid & (COUT_ - 1);   // fastest: output channel
    int ck = tid >> 6;            // c*K + k
    wT[tid] = w[o * (C_ * K_) + ck];
}

// ---------------------------------------------------------------------------
// Main kernel: one thread per output pixel, 64 accumulators (all out chans).
// Loop order: ctile (8 ch) -> k (9 taps) -> c. Keeps the live x working set
// at ~24 KB/block (L1-resident) instead of ~100KB+ sweeping all 64 channels
// per tap (R1: 265 MB HBM over-fetch; R2's extra waves thrashed L2 -> 353 MB).
// Block swizzle groups 32 consecutive pixel-blocks per XCD for L2 locality.
// ---------------------------------------------------------------------------
template <bool TW>
__global__ __launch_bounds__(256) void dcn_fwd(
    const float* __restrict__ x,       // (N, C, H, W)
    const float* __restrict__ offset,  // (N, 2*K, H, W)  ch = 2k (+0=y, +1=x)
    const float* __restrict__ mask,    // (N, K, H, W)
    const float* __restrict__ wptr,    // TW ? wT[ck*64+o] : weight[o*576+ck]
    const float* __restrict__ bias,    // (Cout,)
    float* __restrict__ out)           // (N, Cout, H, W)
{
    // XCD-contiguous swizzle: HW round-robins blocks across 8 XCDs; remap so
    // each XCD's 32 blocks are CONSECUTIVE pixel-blocks (adjacent rows share
    // halo rows in that XCD's L2). Bijection on [0,256).
    const int lb  = (blockIdx.x & 7) * 32 + (blockIdx.x >> 3);
    const int pix = lb * 256 + threadIdx.x;    // 0 .. 65535
    const int n   = pix >> 14;          // / HW_
    const int hw  = pix & (HW_ - 1);
    const int ho  = hw >> 7;            // / W_
    const int wo  = hw & (W_ - 1);

    float acc[COUT_];
#pragma unroll
    for (int o = 0; o < COUT_; ++o) acc[o] = bias[o];

    const float* xn   = x      + n * (C_ * HW_);
    const float* offn = offset + n * (2 * K_ * HW_) + hw;
    const float* mn   = mask   + n * (K_ * HW_)     + hw;

    for (int ct = 0; ct < C_; ct += CT_) {
#pragma unroll
        for (int k = 0; k < K_; ++k) {
            const int ky = k / KW_;
            const int kx = k - ky * KW_;

            const float off_y = offn[(2 * k + 0) * HW_];
            const float off_x = offn[(2 * k + 1) * HW_];
            const float m     = mn[k * HW_];

            const float py = (float)(ho - 1 + ky) + off_y;   // stride=1, pad=1, dil=1
            const float px = (float)(wo - 1 + kx) + off_x;

            const float y0f = floorf(py);
            const float x0f = floorf(px);
            const float ly  = py - y0f;
            const float lx  = px - x0f;

            const int y0 = (int)y0f, x0 = (int)x0f;
            const int y1 = y0 + 1,   x1 = x0 + 1;

            const bool vy0 = (y0 >= 0) && (y0 < H_);
            const bool vy1 = (y1 >= 0) && (y1 < H_);
            const bool vx0 = (x0 >= 0) && (x0 < W_);
            const bool vx1 = (x1 >= 0) && (x1 < W_);

            const int cy0 = min(max(y0, 0), H_ - 1);
            const int cy1 = min(max(y1, 0), H_ - 1);
            const int cx0 = min(max(x0, 0), W_ - 1);
            const int cx1 = min(max(x1, 0), W_ - 1);

            const int i00 = cy0 * W_ + cx0;
            const int i01 = cy0 * W_ + cx1;
            const int i10 = cy1 * W_ + cx0;
            const int i11 = cy1 * W_ + cx1;

            // fold validity + mask into the 4 bilinear corner coefficients
            const float f00 = (1.f - ly) * (1.f - lx) * m * ((vy0 && vx0) ? 1.f : 0.f);
            const float f01 = (1.f - ly) * lx         * m * ((vy0 && vx1) ? 1.f : 0.f);
            const float f10 = ly         * (1.f - lx) * m * ((vy1 && vx0) ? 1.f : 0.f);
            const float f11 = ly         * lx         * m * ((vy1 && vx1) ? 1.f : 0.f);

#pragma unroll
            for (int cc = 0; cc < CT_; ++cc) {
                const int c = ct + cc;
                const float* xc = xn + c * HW_;
                const float val = fmaf(f00, xc[i00],
                                 fmaf(f01, xc[i01],
                                 fmaf(f10, xc[i10],
                                      f11 * xc[i11])));
                const int ck = c * K_ + k;
                if (TW) {
                    const float* wrow = wptr + ck * COUT_;   // contiguous, uniform
#pragma unroll
                    for (int o = 0; o < COUT_; ++o)
                        acc[o] = fmaf(wrow[o], val, acc[o]);
                } else {
#pragma unroll
                    for (int o = 0; o < COUT_; ++o)
                        acc[o] = fmaf(wptr[o * (C_ * K_) + ck], val, acc[o]);
                }
            }
        }
    }

    float* outp = out + n * (COUT_ * HW_) + hw;
#pragma unroll
    for (int o = 0; o < COUT_; ++o) outp[o * HW_] = acc[o];
}

extern "C" void kernel_launch(void* const* d_in, const int* in_sizes, int n_in,
                              void* d_out, int out_size, void* d_ws, size_t ws_size,
                              hipStream_t stream) {
    const float* x      = (const float*)d_in[0];
    const float* offset = (const float*)d_in[1];
    const float* mask   = (const float*)d_in[2];
    const float* weight = (const float*)d_in[3];
    const float* bias   = (const float*)d_in[4];
    float* out = (float*)d_out;

    const size_t wT_bytes = (size_t)COUT_ * C_ * K_ * sizeof(float);  // 147456

    const int total_pix = N_ * HW_;           // 65536
    const int blocks    = total_pix / 256;    // 256

    if (ws_size >= wT_bytes) {
        float* wT = (float*)d_ws;
        transpose_weight<<<(COUT_ * C_ * K_ + 255) / 256, 256, 0, stream>>>(weight, wT);
        dcn_fwd<true><<<blocks, 256, 0, stream>>>(x, offset, mask, wT, bias, out);
    } else {
        dcn_fwd<false><<<blocks, 256, 0, stream>>>(x, offset, mask, weight, bias, out);
    }
}

// Round 4
// 198.961 us; speedup vs baseline: 2.2155x; 1.4771x over previous
//
#include <hip/hip_runtime.h>

// DCNv2 forward via bf16 MFMA implicit GEMM. Fixed problem size:
#define N_    4
#define C_    64
#define H_    128
#define W_    128
#define KW_   3
#define K_    9
#define COUT_ 64
#define HW_   (H_ * W_)   // 16384

typedef short v8s __attribute__((ext_vector_type(8)));   // 8 bf16 (4 VGPRs)
typedef float v4f __attribute__((ext_vector_type(4)));   // MFMA C/D

typedef unsigned short ushort_t;

static __device__ __forceinline__ ushort_t f2bf(float f) {
    union { float f; unsigned int u; } v; v.f = f;
    unsigned int r = v.u + 0x7FFFu + ((v.u >> 16) & 1u);   // RNE
    return (ushort_t)(r >> 16);
}

// ---------------------------------------------------------------------------
// Prologue: wA2[tap][o][c] = bf16(weight[o][c][tap]).   9*64*64 ushorts (73.7KB)
// A-operand chunk (tap, chalf): A[m][kc] = wA2[tap][m][chalf*32+kc] — for a
// fixed m, k is contiguous -> per-lane 16B fragment loads straight from global.
// ---------------------------------------------------------------------------
__global__ void build_wA(const float* __restrict__ w, ushort_t* __restrict__ wA2) {
    int tid = blockIdx.x * blockDim.x + threadIdx.x;     // 0 .. 36863
    if (tid >= K_ * 64 * 64) return;
    int c   = tid & 63;
    int o   = (tid >> 6) & 63;
    int tap = tid >> 12;
    wA2[tid] = f2bf(w[o * (C_ * K_) + c * K_ + tap]);
}

// ---------------------------------------------------------------------------
// Main kernel: block = 64 pixels x 64 Cout, 4 waves (each a 32x32 out tile as
// 2x2 of 16x16x32 bf16 MFMA). Per tap: build bilinear column tile (64 ck x
// 64 pix, bf16) in LDS, A frags loaded per-lane from global (L1-hot), then
// 8 MFMAs/wave. K-dim order: tap outer, channel inner (A table built to match).
// ---------------------------------------------------------------------------
__global__ __launch_bounds__(256, 4) void dcn_mfma(
    const float* __restrict__ x,       // (N, C, H, W)
    const float* __restrict__ offset,  // (N, 2*K, H, W)
    const float* __restrict__ mask,    // (N, K, H, W)
    const ushort_t* __restrict__ wA2,  // (K, Cout, C) bf16
    const float* __restrict__ bias,    // (Cout,)
    float* __restrict__ out)           // (N, Cout, H, W)
{
    const int tid  = threadIdx.x;
    const int lane = tid & 63;
    const int wv   = tid >> 6;          // wave id 0..3; also channel-group for B-build
    // XCD-contiguous swizzle over 1024 blocks: each XCD's 128 blocks cover
    // 64 consecutive image rows -> halo reuse in that XCD's L2.
    const int lb   = (blockIdx.x & 7) * 128 + (blockIdx.x >> 3);
    const int pix_base = lb * 64;                  // 64 | HW_, never crosses images
    const int n_img = pix_base >> 14;
    const int hwb   = pix_base & (HW_ - 1);

    // B-build identity: one pixel per lane
    const int n  = lane;
    const int hw = hwb + n;
    const int ho = hw >> 7;
    const int wo = hw & (W_ - 1);

    // MFMA identity
    const int wm = wv & 1, wn = wv >> 1;
    const int quad = lane >> 4, l16 = lane & 15;

    const float* xn   = x      + n_img * (C_ * HW_);
    const float* offn = offset + n_img * (2 * K_ * HW_) + hw;
    const float* mn   = mask   + n_img * (K_ * HW_)     + hw;

    __shared__ ushort_t Bl[2][4][64][8];   // [chalf][kgroup][pixel][j]  = 8 KB

    v4f acc[2][2];                         // [mhalf][nhalf]
#pragma unroll
    for (int mh = 0; mh < 2; ++mh)
#pragma unroll
        for (int nh = 0; nh < 2; ++nh)
            acc[mh][nh] = (v4f){0.f, 0.f, 0.f, 0.f};

    for (int tap = 0; tap < K_; ++tap) {
        const int ky = tap / KW_;
        const int kx = tap - ky * KW_;

        // ---- bilinear coefficients for (pixel n, tap) ----
        const float off_y = offn[(2 * tap + 0) * HW_];
        const float off_x = offn[(2 * tap + 1) * HW_];
        const float mval  = mn[tap * HW_];

        const float py = (float)(ho - 1 + ky) + off_y;
        const float px = (float)(wo - 1 + kx) + off_x;
        const float y0f = floorf(py), x0f = floorf(px);
        const float ly = py - y0f, lx = px - x0f;
        const int y0 = (int)y0f, x0 = (int)x0f;
        const int y1 = y0 + 1,   x1 = x0 + 1;
        const bool vy0 = (y0 >= 0) & (y0 < H_);
        const bool vy1 = (y1 >= 0) & (y1 < H_);
        const bool vx0 = (x0 >= 0) & (x0 < W_);
        const bool vx1 = (x1 >= 0) & (x1 < W_);
        const int cy0 = min(max(y0, 0), H_ - 1);
        const int cy1 = min(max(y1, 0), H_ - 1);
        const int cx0 = min(max(x0, 0), W_ - 1);
        const int cx1 = min(max(x1, 0), W_ - 1);
        const int i00 = cy0 * W_ + cx0;
        const int i01 = cy0 * W_ + cx1;
        const int i10 = cy1 * W_ + cx0;
        const int i11 = cy1 * W_ + cx1;
        const float f00 = (1.f - ly) * (1.f - lx) * mval * ((vy0 && vx0) ? 1.f : 0.f);
        const float f01 = (1.f - ly) * lx         * mval * ((vy0 && vx1) ? 1.f : 0.f);
        const float f10 = ly         * (1.f - lx) * mval * ((vy1 && vx0) ? 1.f : 0.f);
        const float f11 = ly         * lx         * mval * ((vy1 && vx1) ? 1.f : 0.f);

        // ---- A fragments for this tap: per-lane 16B global loads (L1-hot) ----
        v8s afr[2][2];   // [mhalf][chalf]
#pragma unroll
        for (int mh = 0; mh < 2; ++mh) {
            const int m = wm * 32 + mh * 16 + l16;
#pragma unroll
            for (int ch = 0; ch < 2; ++ch)
                afr[mh][ch] = *(const v8s*)(wA2 + tap * 4096 + m * 64 + ch * 32 + quad * 8);
        }

        __syncthreads();   // previous tap's MFMA reads of Bl complete

        // ---- build B tile: this thread covers channels wv*8 .. wv*8+7 (x2 halves) ----
#pragma unroll
        for (int ch = 0; ch < 2; ++ch) {
            float v[8];
#pragma unroll
            for (int i = 0; i < 8; ++i) {
                const float* xc = xn + (ch * 32 + wv * 8 + i) * HW_;
                v[i] = fmaf(f00, xc[i00],
                       fmaf(f01, xc[i01],
                       fmaf(f10, xc[i10],
                            f11 * xc[i11])));
            }
            ushort_t pk[8];
#pragma unroll
            for (int i = 0; i < 8; ++i) pk[i] = f2bf(v[i]);
            *(v8s*)&Bl[ch][wv][n][0] = *(const v8s*)pk;   // contiguous b128/wave
        }

        __syncthreads();

        // ---- MFMA: 2 chunks (chalf) x 2x2 subtiles ----
#pragma unroll
        for (int ch = 0; ch < 2; ++ch) {
            v8s bfr[2];
#pragma unroll
            for (int nh = 0; nh < 2; ++nh)
                bfr[nh] = *(const v8s*)&Bl[ch][quad][wn * 32 + nh * 16 + l16][0];
#pragma unroll
            for (int mh = 0; mh < 2; ++mh)
#pragma unroll
                for (int nh = 0; nh < 2; ++nh)
                    acc[mh][nh] = __builtin_amdgcn_mfma_f32_16x16x32_bf16(
                        afr[mh][ch], bfr[nh], acc[mh][nh], 0, 0, 0);
        }
    }

    // ---- epilogue: D[m = quad*4+reg][p = l16], + bias ----
    float* outp = out + n_img * (COUT_ * HW_) + hwb;
#pragma unroll
    for (int mh = 0; mh < 2; ++mh)
#pragma unroll
        for (int nh = 0; nh < 2; ++nh) {
            const int col = wn * 32 + nh * 16 + l16;
#pragma unroll
            for (int r = 0; r < 4; ++r) {
                const int m = wm * 32 + mh * 16 + quad * 4 + r;
                outp[m * HW_ + col] = acc[mh][nh][r] + bias[m];
            }
        }
}

// ---------------------------------------------------------------------------
// Fallback (ws too small): R3-style direct fp32 kernel, correctness-first.
// ---------------------------------------------------------------------------
__global__ __launch_bounds__(256) void dcn_fallback(
    const float* __restrict__ x, const float* __restrict__ offset,
    const float* __restrict__ mask, const float* __restrict__ wptr,
    const float* __restrict__ bias, float* __restrict__ out)
{
    const int pix = blockIdx.x * 256 + threadIdx.x;
    const int n = pix >> 14, hw = pix & (HW_ - 1);
    const int ho = hw >> 7,  wo = hw & (W_ - 1);
    float acc[COUT_];
#pragma unroll
    for (int o = 0; o < COUT_; ++o) acc[o] = bias[o];
    const float* xn   = x + n * (C_ * HW_);
    const float* offn = offset + n * (2 * K_ * HW_) + hw;
    const float* mn   = mask + n * (K_ * HW_) + hw;
    for (int ct = 0; ct < C_; ct += 8) {
        for (int k = 0; k < K_; ++k) {
            const int ky = k / KW_, kx = k - ky * KW_;
            const float off_y = offn[(2 * k + 0) * HW_];
            const float off_x = offn[(2 * k + 1) * HW_];
            const float m = mn[k * HW_];
            const float py = (float)(ho - 1 + ky) + off_y;
            const float px = (float)(wo - 1 + kx) + off_x;
            const float y0f = floorf(py), x0f = floorf(px);
            const float ly = py - y0f, lx = px - x0f;
            const int y0 = (int)y0f, x0 = (int)x0f, y1 = y0 + 1, x1 = x0 + 1;
            const bool vy0 = (y0 >= 0) & (y0 < H_), vy1 = (y1 >= 0) & (y1 < H_);
            const bool vx0 = (x0 >= 0) & (x0 < W_), vx1 = (x1 >= 0) & (x1 < W_);
            const int cy0 = min(max(y0, 0), H_ - 1), cy1 = min(max(y1, 0), H_ - 1);
            const int cx0 = min(max(x0, 0), W_ - 1), cx1 = min(max(x1, 0), W_ - 1);
            const int i00 = cy0 * W_ + cx0, i01 = cy0 * W_ + cx1;
            const int i10 = cy1 * W_ + cx0, i11 = cy1 * W_ + cx1;
            const float f00 = (1.f - ly) * (1.f - lx) * m * ((vy0 && vx0) ? 1.f : 0.f);
            const float f01 = (1.f - ly) * lx * m * ((vy0 && vx1) ? 1.f : 0.f);
            const float f10 = ly * (1.f - lx) * m * ((vy1 && vx0) ? 1.f : 0.f);
            const float f11 = ly * lx * m * ((vy1 && vx1) ? 1.f : 0.f);
            for (int cc = 0; cc < 8; ++cc) {
                const int c = ct + cc;
                const float* xc = xn + c * HW_;
                const float val = fmaf(f00, xc[i00], fmaf(f01, xc[i01],
                                  fmaf(f10, xc[i10], f11 * xc[i11])));
#pragma unroll
                for (int o = 0; o < COUT_; ++o)
                    acc[o] = fmaf(wptr[o * (C_ * K_) + c * K_ + k], val, acc[o]);
            }
        }
    }
    float* outp = out + n * (COUT_ * HW_) + hw;
#pragma unroll
    for (int o = 0; o < COUT_; ++o) outp[o * HW_] = acc[o];
}

extern "C" void kernel_launch(void* const* d_in, const int* in_sizes, int n_in,
                              void* d_out, int out_size, void* d_ws, size_t ws_size,
                              hipStream_t stream) {
    const float* x      = (const float*)d_in[0];
    const float* offset = (const float*)d_in[1];
    const float* mask   = (const float*)d_in[2];
    const float* weight = (const float*)d_in[3];
    const float* bias   = (const float*)d_in[4];
    float* out = (float*)d_out;

    const size_t wA_bytes = (size_t)K_ * 64 * 64 * sizeof(ushort_t);   // 73728

    if (ws_size >= wA_bytes) {
        ushort_t* wA2 = (ushort_t*)d_ws;
        build_wA<<<(K_ * 64 * 64 + 255) / 256, 256, 0, stream>>>(weight, wA2);
        dcn_mfma<<<(N_ * HW_) / 64, 256, 0, stream>>>(x, offset, mask, wA2, bias, out);
    } else {
        dcn_fallback<<<(N_ * HW_) / 256, 256, 0, stream>>>(x, offset, mask, weight, bias, out);
    }
}

// Round 5
// 195.893 us; speedup vs baseline: 2.2502x; 1.0157x over previous
//
#include <hip/hip_runtime.h>

// DCNv2 forward = im2col (bf16 cols) + barrier-free MFMA GEMM.
#define N_    4
#define C_    64
#define H_    128
#define W_    128
#define KW_   3
#define K_    9
#define COUT_ 64
#define HW_   (H_ * W_)     // 16384
#define NPIX  (N_ * HW_)    // 65536
#define KK_   (C_ * K_)     // 576
#define KG_   (KK_ / 8)     // 72 groups of 8 k-elements

typedef short v8s __attribute__((ext_vector_type(8)));   // 8 bf16 (4 VGPRs)
typedef float v4f __attribute__((ext_vector_type(4)));   // MFMA C/D
typedef unsigned short u16;

static __device__ __forceinline__ u16 f2bf(float f) {
    union { float f; unsigned int u; } v; v.f = f;
    unsigned int r = v.u + 0x7FFFu + ((v.u >> 16) & 1u);   // RNE
    return (u16)(r >> 16);
}

// ---------------------------------------------------------------------------
// wA2[tap][o][c] = bf16(weight[o][c][tap]); GEMM k-index = tap*64 + c.
// A-fragment (16x16x32, k-chunk kc): lane reads 16B at
//   wA2 + (kc/2)*4096 + m*64 + (kc&1)*32 + quad*8      (R4-verified layout)
// ---------------------------------------------------------------------------
__global__ void build_wA(const float* __restrict__ w, u16* __restrict__ wA2) {
    int tid = blockIdx.x * blockDim.x + threadIdx.x;     // 0 .. 36863
    if (tid >= K_ * 64 * 64) return;
    int c   = tid & 63;
    int o   = (tid >> 6) & 63;
    int tap = tid >> 12;
    wA2[tid] = f2bf(w[o * (C_ * K_) + c * K_ + tap]);
}

// ---------------------------------------------------------------------------
// im2col: thread = (pixel, tap). Barrier-free, low VGPR, 2304 blocks -> max
// TLP for the latency-bound gather. cols[kg][px][j] bf16, kg = tap*8 + c/8,
// j = c%8: per-lane 16B coalesced stores (1 KB/wave), and GEMM B-fragments
// become contiguous per-lane 16B loads.
// Grid: (256, 9); x swizzled so each XCD sees 32 consecutive pixel-blocks
// (x-slab ~2.2 MB, L2-resident — the R3 fix that cut FETCH 265->13 MB).
// ---------------------------------------------------------------------------
__global__ __launch_bounds__(256) void im2col(
    const float* __restrict__ x,       // (N, C, H, W)
    const float* __restrict__ offset,  // (N, 2*K, H, W)
    const float* __restrict__ mask,    // (N, K, H, W)
    u16* __restrict__ cols)            // (KG, NPIX, 8)
{
    const int tap = blockIdx.y;
    const int bx  = (blockIdx.x & 7) * 32 + (blockIdx.x >> 3);   // XCD swizzle
    const int px  = bx * 256 + threadIdx.x;
    const int n   = px >> 14;
    const int hw  = px & (HW_ - 1);
    const int ho  = hw >> 7;
    const int wo  = hw & (W_ - 1);

    const int ky = tap / KW_;
    const int kx = tap - ky * KW_;

    const float off_y = offset[n * (2 * K_ * HW_) + (2 * tap + 0) * HW_ + hw];
    const float off_x = offset[n * (2 * K_ * HW_) + (2 * tap + 1) * HW_ + hw];
    const float mval  = mask[n * (K_ * HW_) + tap * HW_ + hw];

    const float py = (float)(ho - 1 + ky) + off_y;   // stride=1, pad=1, dil=1
    const float px_ = (float)(wo - 1 + kx) + off_x;
    const float y0f = floorf(py), x0f = floorf(px_);
    const float ly = py - y0f, lx = px_ - x0f;
    const int y0 = (int)y0f, x0 = (int)x0f;
    const int y1 = y0 + 1,   x1 = x0 + 1;
    const bool vy0 = (y0 >= 0) & (y0 < H_);
    const bool vy1 = (y1 >= 0) & (y1 < H_);
    const bool vx0 = (x0 >= 0) & (x0 < W_);
    const bool vx1 = (x1 >= 0) & (x1 < W_);
    const int cy0 = min(max(y0, 0), H_ - 1);
    const int cy1 = min(max(y1, 0), H_ - 1);
    const int cx0 = min(max(x0, 0), W_ - 1);
    const int cx1 = min(max(x1, 0), W_ - 1);
    const int i00 = cy0 * W_ + cx0;
    const int i01 = cy0 * W_ + cx1;
    const int i10 = cy1 * W_ + cx0;
    const int i11 = cy1 * W_ + cx1;
    const float f00 = (1.f - ly) * (1.f - lx) * mval * ((vy0 && vx0) ? 1.f : 0.f);
    const float f01 = (1.f - ly) * lx         * mval * ((vy0 && vx1) ? 1.f : 0.f);
    const float f10 = ly         * (1.f - lx) * mval * ((vy1 && vx0) ? 1.f : 0.f);
    const float f11 = ly         * lx         * mval * ((vy1 && vx1) ? 1.f : 0.f);

    const float* xn = x + n * (C_ * HW_);

    // 8 chunks of 8 channels; chunks independent -> loads pipeline freely.
    for (int cc = 0; cc < 8; ++cc) {
        float v[8];
#pragma unroll
        for (int i = 0; i < 8; ++i) {
            const float* xc = xn + (cc * 8 + i) * HW_;
            v[i] = fmaf(f00, xc[i00],
                   fmaf(f01, xc[i01],
                   fmaf(f10, xc[i10],
                        f11 * xc[i11])));
        }
        u16 pk[8];
#pragma unroll
        for (int i = 0; i < 8; ++i) pk[i] = f2bf(v[i]);
        *(v8s*)(cols + ((size_t)(tap * 8 + cc) * NPIX + px) * 8) = *(const v8s*)pk;
    }
}

// ---------------------------------------------------------------------------
// GEMM: out[o, px] = sum_k wA[k,o] * cols[k,px].  M=64, K=576, N=65536.
// Block = 256 thr / 4 waves; wave tile = 64 cout x 32 px (4x2 of 16x16x32).
// NO LDS, NO barriers: A frags per-lane 16B from wA2 (L1-hot), B frags
// per-lane 16B from cols (streamed once, L2/L3). Compiler pipelines K-loop.
// ---------------------------------------------------------------------------
__global__ __launch_bounds__(256) void gemm_mfma(
    const u16* __restrict__ cols,      // (KG, NPIX, 8)
    const u16* __restrict__ wA2,       // (K, 64, 64)
    const float* __restrict__ bias,
    float* __restrict__ out)           // (N, Cout, H, W)
{
    const int lane = threadIdx.x & 63;
    const int wv   = threadIdx.x >> 6;
    const int quad = lane >> 4;
    const int l16  = lane & 15;

    const int pxb = blockIdx.x * 128;        // 128 | HW_: block stays in one image
    const int pxw = pxb + wv * 32;           // this wave's 32-pixel strip
    const int n   = pxb >> 14;
    const int hwb = pxw & (HW_ - 1);

    v4f acc[4][2];                           // [mh: cout 16s][nh: px 16s]
#pragma unroll
    for (int mh = 0; mh < 4; ++mh)
#pragma unroll
        for (int nh = 0; nh < 2; ++nh)
            acc[mh][nh] = (v4f){0.f, 0.f, 0.f, 0.f};

    for (int kc = 0; kc < KK_ / 32; ++kc) {  // 18 k-chunks of 32
        v8s afr[4];
#pragma unroll
        for (int mh = 0; mh < 4; ++mh)
            afr[mh] = *(const v8s*)(wA2 + (kc >> 1) * 4096 + (mh * 16 + l16) * 64
                                        + (kc & 1) * 32 + quad * 8);
        v8s bfr[2];
#pragma unroll
        for (int nh = 0; nh < 2; ++nh)
            bfr[nh] = *(const v8s*)(cols + ((size_t)(kc * 4 + quad) * NPIX
                                            + pxw + nh * 16 + l16) * 8);
#pragma unroll
        for (int mh = 0; mh < 4; ++mh)
#pragma unroll
            for (int nh = 0; nh < 2; ++nh)
                acc[mh][nh] = __builtin_amdgcn_mfma_f32_16x16x32_bf16(
                    afr[mh], bfr[nh], acc[mh][nh], 0, 0, 0);
    }

    // D layout (verified R4): col = l16 (px), row = quad*4 + r (cout)
    float* outb = out + n * (COUT_ * HW_);
#pragma unroll
    for (int mh = 0; mh < 4; ++mh)
#pragma unroll
        for (int nh = 0; nh < 2; ++nh)
#pragma unroll
            for (int r = 0; r < 4; ++r) {
                const int m = mh * 16 + quad * 4 + r;
                outb[m * HW_ + hwb + nh * 16 + l16] = acc[mh][nh][r] + bias[m];
            }
}

// ---------------------------------------------------------------------------
// Fallback (ws too small for cols): R3-style direct fp32 kernel, no ws needed.
// ---------------------------------------------------------------------------
__global__ __launch_bounds__(256) void dcn_fallback(
    const float* __restrict__ x, const float* __restrict__ offset,
    const float* __restrict__ mask, const float* __restrict__ wptr,
    const float* __restrict__ bias, float* __restrict__ out)
{
    const int pix = blockIdx.x * 256 + threadIdx.x;
    const int n = pix >> 14, hw = pix & (HW_ - 1);
    const int ho = hw >> 7,  wo = hw & (W_ - 1);
    float acc[COUT_];
#pragma unroll
    for (int o = 0; o < COUT_; ++o) acc[o] = bias[o];
    const float* xn   = x + n * (C_ * HW_);
    const float* offn = offset + n * (2 * K_ * HW_) + hw;
    const float* mn   = mask + n * (K_ * HW_) + hw;
    for (int ct = 0; ct < C_; ct += 8) {
        for (int k = 0; k < K_; ++k) {
            const int ky = k / KW_, kx = k - ky * KW_;
            const float off_y = offn[(2 * k + 0) * HW_];
            const float off_x = offn[(2 * k + 1) * HW_];
            const float m = mn[k * HW_];
            const float py = (float)(ho - 1 + ky) + off_y;
            const float px = (float)(wo - 1 + kx) + off_x;
            const float y0f = floorf(py), x0f = floorf(px);
            const float ly = py - y0f, lx = px - x0f;
            const int y0 = (int)y0f, x0 = (int)x0f, y1 = y0 + 1, x1 = x0 + 1;
            const bool vy0 = (y0 >= 0) & (y0 < H_), vy1 = (y1 >= 0) & (y1 < H_);
            const bool vx0 = (x0 >= 0) & (x0 < W_), vx1 = (x1 >= 0) & (x1 < W_);
            const int cy0 = min(max(y0, 0), H_ - 1), cy1 = min(max(y1, 0), H_ - 1);
            const int cx0 = min(max(x0, 0), W_ - 1), cx1 = min(max(x1, 0), W_ - 1);
            const int i00 = cy0 * W_ + cx0, i01 = cy0 * W_ + cx1;
            const int i10 = cy1 * W_ + cx0, i11 = cy1 * W_ + cx1;
            const float f00 = (1.f - ly) * (1.f - lx) * m * ((vy0 && vx0) ? 1.f : 0.f);
            const float f01 = (1.f - ly) * lx * m * ((vy0 && vx1) ? 1.f : 0.f);
            const float f10 = ly * (1.f - lx) * m * ((vy1 && vx0) ? 1.f : 0.f);
            const float f11 = ly * lx * m * ((vy1 && vx1) ? 1.f : 0.f);
            for (int cc = 0; cc < 8; ++cc) {
                const int c = ct + cc;
                const float* xc = xn + c * HW_;
                const float val = fmaf(f00, xc[i00], fmaf(f01, xc[i01],
                                  fmaf(f10, xc[i10], f11 * xc[i11])));
#pragma unroll
                for (int o = 0; o < COUT_; ++o)
                    acc[o] = fmaf(wptr[o * (C_ * K_) + c * K_ + k], val, acc[o]);
            }
        }
    }
    float* outp = out + n * (COUT_ * HW_) + hw;
#pragma unroll
    for (int o = 0; o < COUT_; ++o) outp[o * HW_] = acc[o];
}

extern "C" void kernel_launch(void* const* d_in, const int* in_sizes, int n_in,
                              void* d_out, int out_size, void* d_ws, size_t ws_size,
                              hipStream_t stream) {
    const float* x      = (const float*)d_in[0];
    const float* offset = (const float*)d_in[1];
    const float* mask   = (const float*)d_in[2];
    const float* weight = (const float*)d_in[3];
    const float* bias   = (const float*)d_in[4];
    float* out = (float*)d_out;

    const size_t cols_bytes = (size_t)KG_ * NPIX * 8 * sizeof(u16);  // 75.5 MB
    const size_t wA_bytes   = (size_t)K_ * 64 * 64 * sizeof(u16);    // 73.7 KB

    if (ws_size >= cols_bytes + wA_bytes) {
        u16* cols = (u16*)d_ws;
        u16* wA2  = (u16*)((char*)d_ws + cols_bytes);
        build_wA<<<(K_ * 64 * 64 + 255) / 256, 256, 0, stream>>>(weight, wA2);
        dim3 g(NPIX / 256, K_);
        im2col<<<g, 256, 0, stream>>>(x, offset, mask, cols);
        gemm_mfma<<<NPIX / 128, 256, 0, stream>>>(cols, wA2, bias, out);
    } else {
        dcn_fallback<<<NPIX / 256, 256, 0, stream>>>(x, offset, mask, weight, bias, out);
    }
}

// Round 6
// 184.926 us; speedup vs baseline: 2.3836x; 1.0593x over previous
//
#include <hip/hip_runtime.h>

// DCNv2 forward = NHWC transpose + lane=channel im2col (bf16 cols) + MFMA GEMM.
#define N_    4
#define C_    64
#define H_    128
#define W_    128
#define KW_   3
#define K_    9
#define COUT_ 64
#define HW_   (H_ * W_)     // 16384
#define NPIX  (N_ * HW_)    // 65536
#define KK_   (C_ * K_)     // 576

typedef short v8s __attribute__((ext_vector_type(8)));   // 8 bf16 (4 VGPRs)
typedef float v4f __attribute__((ext_vector_type(4)));   // MFMA C/D
typedef unsigned short u16;

static __device__ __forceinline__ u16 f2bf(float f) {
    union { float f; unsigned int u; } v; v.f = f;
    unsigned int r = v.u + 0x7FFFu + ((v.u >> 16) & 1u);   // RNE
    return (u16)(r >> 16);
}

// ---------------------------------------------------------------------------
// wA3[o][k], k = tap*64 + c  (matches cols2 k-ordering).  64x576 bf16, 73.7 KB.
// A-fragment (16x16x32): lane reads 16B at wA3 + m*576 + kc*32 + quad*8.
// ---------------------------------------------------------------------------
__global__ void build_wA(const float* __restrict__ w, u16* __restrict__ wA3) {
    int tid = blockIdx.x * blockDim.x + threadIdx.x;     // 0 .. 36863
    if (tid >= COUT_ * KK_) return;
    int k   = tid % KK_;          // tap*64 + c
    int o   = tid / KK_;
    int c   = k & 63;
    int tap = k >> 6;
    wA3[tid] = f2bf(w[o * (C_ * K_) + c * K_ + tap]);
}

// ---------------------------------------------------------------------------
// NCHW -> NHWC transpose of x: xh[n][hw][c] = x[n][c][hw].  LDS-tiled 64x64.
// ---------------------------------------------------------------------------
__global__ __launch_bounds__(256) void transpose_x(
    const float* __restrict__ x, float* __restrict__ xh)
{
    const int n   = blockIdx.x >> 8;            // 4 images x 256 hw-tiles
    const int hw0 = (blockIdx.x & 255) * 64;
    const int j   = threadIdx.x & 63;           // lane
    const int r0  = threadIdx.x >> 6;           // 0..3

    __shared__ float tile[64][65];              // [hw][c], pad -> conflict-free
    const float* xb = x + n * (C_ * HW_);
#pragma unroll
    for (int i = 0; i < 16; ++i) {
        const int c = i * 4 + r0;
        tile[j][c] = xb[c * HW_ + hw0 + j];     // lane j = hw: coalesced 256B
    }
    __syncthreads();
    float* xo = xh + ((size_t)n * HW_ + hw0) * 64;
#pragma unroll
    for (int i = 0; i < 16; ++i) {
        const int hr = i * 4 + r0;
        xo[hr * 64 + j] = tile[hr][j];          // lane j = c: coalesced 256B
    }
}

// ---------------------------------------------------------------------------
// im2col, lane = channel. Every gather address is WAVE-UNIFORM: one corner
// load = 256B contiguous (4 lines) and covers all 64 channels -- vs R5's
// lane=pixel divergent gathers (~18 lines/load, L1-throughput bound).
// cols2[px][k] bf16, k = tap*64 + c: store is 128B contiguous per (px,tap);
// GEMM B-fragments become per-lane 16B contiguous loads.
// Wave handles 8 px x 9 taps. Grid 2048 (8 blocks/CU, 32 waves/CU), XCD
// swizzle keeps each XCD's xh slab at ~2 MB (L2-resident).
// ---------------------------------------------------------------------------
__global__ __launch_bounds__(256) void im2col(
    const float* __restrict__ xh,      // (N, HW, C)
    const float* __restrict__ offset,  // (N, 2*K, H, W)
    const float* __restrict__ mask,    // (N, K, H, W)
    u16* __restrict__ cols2)           // (NPIX, KK)
{
    const int lane = threadIdx.x & 63;          // channel
    const int wv   = threadIdx.x >> 6;
    const int lb   = (blockIdx.x & 7) * 256 + (blockIdx.x >> 3);   // XCD swizzle
    const int px0  = lb * 32 + wv * 8;          // this wave's 8 pixels

    for (int p = 0; p < 8; ++p) {
        const int px = px0 + p;
        const int n  = px >> 14;
        const int hw = px & (HW_ - 1);
        const int ho = hw >> 7;
        const int wo = hw & (W_ - 1);

        const float* offp = offset + n * (2 * K_ * HW_) + hw;
        const float* mp   = mask   + n * (K_ * HW_)     + hw;
        const float* xb   = xh + ((size_t)n * HW_) * 64 + lane;
        u16* cp = cols2 + (size_t)px * KK_ + lane;

        // hoist all 27 coefficient loads (independent -> one latency)
        float offy[K_], offx[K_], mv[K_];
#pragma unroll
        for (int t = 0; t < K_; ++t) {
            offy[t] = offp[(2 * t + 0) * HW_];
            offx[t] = offp[(2 * t + 1) * HW_];
            mv[t]   = mp[t * HW_];
        }

#pragma unroll
        for (int t = 0; t < K_; ++t) {
            const int ky = t / KW_;
            const int kx = t - ky * KW_;
            const float py = (float)(ho - 1 + ky) + offy[t];
            const float qx = (float)(wo - 1 + kx) + offx[t];
            const float y0f = floorf(py), x0f = floorf(qx);
            const float ly = py - y0f, lx = qx - x0f;
            const int y0 = (int)y0f, x0 = (int)x0f;
            const int y1 = y0 + 1,   x1 = x0 + 1;
            const bool vy0 = (y0 >= 0) & (y0 < H_);
            const bool vy1 = (y1 >= 0) & (y1 < H_);
            const bool vx0 = (x0 >= 0) & (x0 < W_);
            const bool vx1 = (x1 >= 0) & (x1 < W_);
            const int cy0 = min(max(y0, 0), H_ - 1);
            const int cy1 = min(max(y1, 0), H_ - 1);
            const int cx0 = min(max(x0, 0), W_ - 1);
            const int cx1 = min(max(x1, 0), W_ - 1);
            const float f00 = (1.f - ly) * (1.f - lx) * mv[t] * ((vy0 && vx0) ? 1.f : 0.f);
            const float f01 = (1.f - ly) * lx         * mv[t] * ((vy0 && vx1) ? 1.f : 0.f);
            const float f10 = ly         * (1.f - lx) * mv[t] * ((vy1 && vx0) ? 1.f : 0.f);
            const float f11 = ly         * lx         * mv[t] * ((vy1 && vx1) ? 1.f : 0.f);

            // 4 wave-uniform 256B corner loads: all channels at once
            const float v00 = xb[(size_t)(cy0 * W_ + cx0) * 64];
            const float v01 = xb[(size_t)(cy0 * W_ + cx1) * 64];
            const float v10 = xb[(size_t)(cy1 * W_ + cx0) * 64];
            const float v11 = xb[(size_t)(cy1 * W_ + cx1) * 64];

            const float val = fmaf(f00, v00, fmaf(f01, v01,
                              fmaf(f10, v10, f11 * v11)));
            cp[t * 64] = f2bf(val);             // 128B contiguous wave store
        }
    }
}

// ---------------------------------------------------------------------------
// GEMM: out[o, px] = sum_k wA3[o,k] * cols2[px,k].  M=64, K=576, N=65536.
// Block = 4 waves, wave tile = 64 cout x 16 px (4x1 of 16x16x32). Grid 1024
// -> 16 waves/CU. No LDS/barriers; A and B frags are per-lane 16B loads.
// ---------------------------------------------------------------------------
__global__ __launch_bounds__(256) void gemm_mfma(
    const u16* __restrict__ cols2,     // (NPIX, KK)
    const u16* __restrict__ wA3,       // (COUT, KK)
    const float* __restrict__ bias,
    float* __restrict__ out)           // (N, Cout, H, W)
{
    const int lane = threadIdx.x & 63;
    const int wv   = threadIdx.x >> 6;
    const int quad = lane >> 4;
    const int l16  = lane & 15;

    const int pxw = blockIdx.x * 64 + wv * 16;   // wave's 16-pixel strip
    const int n   = pxw >> 14;                   // 64 | HW_: never crosses images
    const int hwb = pxw & (HW_ - 1);

    v4f acc[4];
#pragma unroll
    for (int mh = 0; mh < 4; ++mh) acc[mh] = (v4f){0.f, 0.f, 0.f, 0.f};

    const u16* bp = cols2 + (size_t)(pxw + l16) * KK_ + quad * 8;
    const u16* ap = wA3 + (size_t)l16 * KK_ + quad * 8;

    for (int kc = 0; kc < KK_ / 32; ++kc) {      // 18 chunks of 32
        const v8s bfr = *(const v8s*)(bp + kc * 32);
        v8s afr[4];
#pragma unroll
        for (int mh = 0; mh < 4; ++mh)
            afr[mh] = *(const v8s*)(ap + mh * 16 * KK_ + kc * 32);
#pragma unroll
        for (int mh = 0; mh < 4; ++mh)
            acc[mh] = __builtin_amdgcn_mfma_f32_16x16x32_bf16(
                afr[mh], bfr, acc[mh], 0, 0, 0);
    }

    // D layout (R4-verified): col = l16 (px), row = quad*4 + r (cout)
    float* outb = out + n * (COUT_ * HW_);
#pragma unroll
    for (int mh = 0; mh < 4; ++mh)
#pragma unroll
        for (int r = 0; r < 4; ++r) {
            const int m = mh * 16 + quad * 4 + r;
            outb[m * HW_ + hwb + l16] = acc[mh][r] + bias[m];
        }
}

// ---------------------------------------------------------------------------
// Fallback (ws too small): R3-style direct fp32 kernel, no ws needed.
// ---------------------------------------------------------------------------
__global__ __launch_bounds__(256) void dcn_fallback(
    const float* __restrict__ x, const float* __restrict__ offset,
    const float* __restrict__ mask, const float* __restrict__ wptr,
    const float* __restrict__ bias, float* __restrict__ out)
{
    const int pix = blockIdx.x * 256 + threadIdx.x;
    const int n = pix >> 14, hw = pix & (HW_ - 1);
    const int ho = hw >> 7,  wo = hw & (W_ - 1);
    float acc[COUT_];
#pragma unroll
    for (int o = 0; o < COUT_; ++o) acc[o] = bias[o];
    const float* xn   = x + n * (C_ * HW_);
    const float* offn = offset + n * (2 * K_ * HW_) + hw;
    const float* mn   = mask + n * (K_ * HW_) + hw;
    for (int ct = 0; ct < C_; ct += 8) {
        for (int k = 0; k < K_; ++k) {
            const int ky = k / KW_, kx = k - ky * KW_;
            const float off_y = offn[(2 * k + 0) * HW_];
            const float off_x = offn[(2 * k + 1) * HW_];
            const float m = mn[k * HW_];
            const float py = (float)(ho - 1 + ky) + off_y;
            const float px = (float)(wo - 1 + kx) + off_x;
            const float y0f = floorf(py), x0f = floorf(px);
            const float ly = py - y0f, lx = px - x0f;
            const int y0 = (int)y0f, x0 = (int)x0f, y1 = y0 + 1, x1 = x0 + 1;
            const bool vy0 = (y0 >= 0) & (y0 < H_), vy1 = (y1 >= 0) & (y1 < H_);
            const bool vx0 = (x0 >= 0) & (x0 < W_), vx1 = (x1 >= 0) & (x1 < W_);
            const int cy0 = min(max(y0, 0), H_ - 1), cy1 = min(max(y1, 0), H_ - 1);
            const int cx0 = min(max(x0, 0), W_ - 1), cx1 = min(max(x1, 0), W_ - 1);
            const int i00 = cy0 * W_ + cx0, i01 = cy0 * W_ + cx1;
            const int i10 = cy1 * W_ + cx0, i11 = cy1 * W_ + cx1;
            const float f00 = (1.f - ly) * (1.f - lx) * m * ((vy0 && vx0) ? 1.f : 0.f);
            const float f01 = (1.f - ly) * lx * m * ((vy0 && vx1) ? 1.f : 0.f);
            const float f10 = ly * (1.f - lx) * m * ((vy1 && vx0) ? 1.f : 0.f);
            const float f11 = ly * lx * m * ((vy1 && vx1) ? 1.f : 0.f);
            for (int cc = 0; cc < 8; ++cc) {
                const int c = ct + cc;
                const float* xc = xn + c * HW_;
                const float val = fmaf(f00, xc[i00], fmaf(f01, xc[i01],
                                  fmaf(f10, xc[i10], f11 * xc[i11])));
#pragma unroll
                for (int o = 0; o < COUT_; ++o)
                    acc[o] = fmaf(wptr[o * (C_ * K_) + c * K_ + k], val, acc[o]);
            }
        }
    }
    float* outp = out + n * (COUT_ * HW_) + hw;
#pragma unroll
    for (int o = 0; o < COUT_; ++o) outp[o * HW_] = acc[o];
}

extern "C" void kernel_launch(void* const* d_in, const int* in_sizes, int n_in,
                              void* d_out, int out_size, void* d_ws, size_t ws_size,
                              hipStream_t stream) {
    const float* x      = (const float*)d_in[0];
    const float* offset = (const float*)d_in[1];
    const float* mask   = (const float*)d_in[2];
    const float* weight = (const float*)d_in[3];
    const float* bias   = (const float*)d_in[4];
    float* out = (float*)d_out;

    const size_t cols_bytes = (size_t)NPIX * KK_ * sizeof(u16);      // 75.5 MB
    const size_t xh_bytes   = (size_t)NPIX * C_ * sizeof(float);     // 16.8 MB
    const size_t wA_bytes   = (size_t)COUT_ * KK_ * sizeof(u16);     // 73.7 KB

    if (ws_size >= cols_bytes + xh_bytes + wA_bytes) {
        u16*   cols2 = (u16*)d_ws;
        float* xh    = (float*)((char*)d_ws + cols_bytes);
        u16*   wA3   = (u16*)((char*)d_ws + cols_bytes + xh_bytes);
        build_wA<<<(COUT_ * KK_ + 255) / 256, 256, 0, stream>>>(weight, wA3);
        transpose_x<<<N_ * 256, 256, 0, stream>>>(x, xh);
        im2col<<<NPIX / 32, 256, 0, stream>>>(xh, offset, mask, cols2);
        gemm_mfma<<<NPIX / 64, 256, 0, stream>>>(cols2, wA3, bias, out);
    } else {
        dcn_fallback<<<NPIX / 256, 256, 0, stream>>>(x, offset, mask, weight, bias, out);
    }
}

// Round 7
// 150.652 us; speedup vs baseline: 2.9259x; 1.2275x over previous
//
#include <hip/hip_runtime.h>

// DCNv2 forward = NHWC transpose + 2-phase im2col (lane-parallel coefs via
// LDS, lane=channel gather) + MFMA GEMM (64x32 wave tile).
#define N_    4
#define C_    64
#define H_    128
#define W_    128
#define KW_   3
#define K_    9
#define COUT_ 64
#define HW_   (H_ * W_)     // 16384
#define NPIX  (N_ * HW_)    // 65536
#define KK_   (C_ * K_)     // 576

typedef short v8s __attribute__((ext_vector_type(8)));   // 8 bf16 (4 VGPRs)
typedef float v4f __attribute__((ext_vector_type(4)));   // MFMA C/D
typedef int   v4i __attribute__((ext_vector_type(4)));
typedef unsigned short u16;

static __device__ __forceinline__ u16 f2bf(float f) {
    union { float f; unsigned int u; } v; v.f = f;
    unsigned int r = v.u + 0x7FFFu + ((v.u >> 16) & 1u);   // RNE
    return (u16)(r >> 16);
}

// ---------------------------------------------------------------------------
// wA3[o][k], k = tap*64 + c  (matches cols2 k-ordering).  64x576 bf16, 73.7 KB.
// A-fragment (16x16x32): lane reads 16B at wA3 + m*576 + kc*32 + quad*8.
// ---------------------------------------------------------------------------
__global__ void build_wA(const float* __restrict__ w, u16* __restrict__ wA3) {
    int tid = blockIdx.x * blockDim.x + threadIdx.x;     // 0 .. 36863
    if (tid >= COUT_ * KK_) return;
    int k   = tid % KK_;          // tap*64 + c
    int o   = tid / KK_;
    int c   = k & 63;
    int tap = k >> 6;
    wA3[tid] = f2bf(w[o * (C_ * K_) + c * K_ + tap]);
}

// ---------------------------------------------------------------------------
// NCHW -> NHWC transpose of x: xh[n][hw][c] = x[n][c][hw].  LDS-tiled 64x64.
// ---------------------------------------------------------------------------
__global__ __launch_bounds__(256) void transpose_x(
    const float* __restrict__ x, float* __restrict__ xh)
{
    const int n   = blockIdx.x >> 8;            // 4 images x 256 hw-tiles
    const int hw0 = (blockIdx.x & 255) * 64;
    const int j   = threadIdx.x & 63;           // lane
    const int r0  = threadIdx.x >> 6;           // 0..3

    __shared__ float tile[64][65];              // [hw][c], pad -> conflict-free
    const float* xb = x + n * (C_ * HW_);
#pragma unroll
    for (int i = 0; i < 16; ++i) {
        const int c = i * 4 + r0;
        tile[j][c] = xb[c * HW_ + hw0 + j];     // lane j = hw: coalesced 256B
    }
    __syncthreads();
    float* xo = xh + ((size_t)n * HW_ + hw0) * 64;
#pragma unroll
    for (int i = 0; i < 16; ++i) {
        const int hr = i * 4 + r0;
        xo[hr * 64 + j] = tile[hr][j];          // lane j = c: coalesced 256B
    }
}

// ---------------------------------------------------------------------------
// im2col, 2-phase. Wave = 8 px x 9 taps = 72 entries.
// Phase 1 (lane = entry): each lane computes the bilinear coefficient set
// {f00..f11, row indices i00..i11} for ONE (px,tap) -> 32B to LDS. This kills
// R6's 64x-redundant uniform VALU (75 us, VALUBusy 63% -> the whole cost).
// Phase 2 (lane = channel): per entry, 2 broadcast ds_read_b128 (uniform
// address -> conflict-free) + 4 wave-uniform 256B corner loads + 3 FMA.
// cols2[px][k] bf16, k = tap*64+c: 128B contiguous wave stores; GEMM B-frags
// are per-lane 16B contiguous loads.
// ---------------------------------------------------------------------------
__global__ __launch_bounds__(256) void im2col(
    const float* __restrict__ xh,      // (N, HW, C)
    const float* __restrict__ offset,  // (N, 2*K, H, W)
    const float* __restrict__ mask,    // (N, K, H, W)
    u16* __restrict__ cols2)           // (NPIX, KK)
{
    const int lane = threadIdx.x & 63;
    const int wv   = threadIdx.x >> 6;
    const int lb   = (blockIdx.x & 7) * 256 + (blockIdx.x >> 3);   // XCD swizzle
    const int px0  = lb * 32 + wv * 8;          // wave's 8 pixels
    const int n    = px0 >> 14;                 // 32 | HW_: uniform per wave

    __shared__ float lds[4][72][8];             // 9216 B: [wave][entry][f4,i4]

    // ---- phase 1: lane-parallel coefficient computation ----
#pragma unroll
    for (int rep = 0; rep < 2; ++rep) {
        const int e = rep * 64 + lane;
        if (e < 72) {
            const int p  = e / 9;               // magic-mul
            const int t  = e - p * 9;
            const int hw = (px0 + p) & (HW_ - 1);
            const int ho = hw >> 7;
            const int wo = hw & (W_ - 1);
            const int ky = t / KW_;
            const int kx = t - ky * KW_;

            const float offy = offset[n * (2 * K_ * HW_) + (2 * t + 0) * HW_ + hw];
            const float offx = offset[n * (2 * K_ * HW_) + (2 * t + 1) * HW_ + hw];
            const float mval = mask[n * (K_ * HW_) + t * HW_ + hw];

            const float py = (float)(ho - 1 + ky) + offy;   // stride=1,pad=1,dil=1
            const float qx = (float)(wo - 1 + kx) + offx;
            const float y0f = floorf(py), x0f = floorf(qx);
            const float ly = py - y0f, lx = qx - x0f;
            const int y0 = (int)y0f, x0 = (int)x0f;
            const int y1 = y0 + 1,   x1 = x0 + 1;
            const bool vy0 = (y0 >= 0) & (y0 < H_);
            const bool vy1 = (y1 >= 0) & (y1 < H_);
            const bool vx0 = (x0 >= 0) & (x0 < W_);
            const bool vx1 = (x1 >= 0) & (x1 < W_);
            const int cy0 = min(max(y0, 0), H_ - 1);
            const int cy1 = min(max(y1, 0), H_ - 1);
            const int cx0 = min(max(x0, 0), W_ - 1);
            const int cx1 = min(max(x1, 0), W_ - 1);

            float* q = &lds[wv][e][0];
            q[0] = (1.f - ly) * (1.f - lx) * mval * ((vy0 && vx0) ? 1.f : 0.f);
            q[1] = (1.f - ly) * lx         * mval * ((vy0 && vx1) ? 1.f : 0.f);
            q[2] = ly         * (1.f - lx) * mval * ((vy1 && vx0) ? 1.f : 0.f);
            q[3] = ly         * lx         * mval * ((vy1 && vx1) ? 1.f : 0.f);
            int* qi = (int*)q;
            qi[4] = cy0 * W_ + cx0;
            qi[5] = cy0 * W_ + cx1;
            qi[6] = cy1 * W_ + cx0;
            qi[7] = cy1 * W_ + cx1;
        }
    }
    __syncthreads();

    // ---- phase 2: lane = channel, wave-uniform gathers ----
    const float* xb = xh + ((size_t)n * HW_) * 64 + lane;
    for (int p = 0; p < 8; ++p) {
        const int px = px0 + p;
        u16* cp = cols2 + (size_t)px * KK_ + lane;
#pragma unroll
        for (int t = 0; t < K_; ++t) {
            const float* q = &lds[wv][p * 9 + t][0];
            const v4f f = *(const v4f*)q;                   // broadcast b128
            const v4i o = *(const v4i*)(q + 4);             // broadcast b128

            const float v00 = xb[(size_t)o.x * 64];         // 256B uniform loads
            const float v01 = xb[(size_t)o.y * 64];
            const float v10 = xb[(size_t)o.z * 64];
            const float v11 = xb[(size_t)o.w * 64];

            const float val = fmaf(f.x, v00, fmaf(f.y, v01,
                              fmaf(f.z, v10, f.w * v11)));
            cp[t * 64] = f2bf(val);                         // 128B wave store
        }
    }
}

// ---------------------------------------------------------------------------
// GEMM: out[o, px] = sum_k wA3[o,k] * cols2[px,k].  M=64, K=576, N=65536.
// Block = 4 waves, wave tile = 64 cout x 32 px (4x2 of 16x16x32): halves
// A-table reload traffic vs R6's 64x16. Grid 512. No LDS/barriers.
// ---------------------------------------------------------------------------
__global__ __launch_bounds__(256) void gemm_mfma(
    const u16* __restrict__ cols2,     // (NPIX, KK)
    const u16* __restrict__ wA3,       // (COUT, KK)
    const float* __restrict__ bias,
    float* __restrict__ out)           // (N, Cout, H, W)
{
    const int lane = threadIdx.x & 63;
    const int wv   = threadIdx.x >> 6;
    const int quad = lane >> 4;
    const int l16  = lane & 15;

    const int pxw = blockIdx.x * 128 + wv * 32;  // wave's 32-pixel strip
    const int n   = pxw >> 14;                   // 128 | HW_: never crosses
    const int hwb = pxw & (HW_ - 1);

    v4f acc[4][2];
#pragma unroll
    for (int mh = 0; mh < 4; ++mh)
#pragma unroll
        for (int nh = 0; nh < 2; ++nh)
            acc[mh][nh] = (v4f){0.f, 0.f, 0.f, 0.f};

    const u16* bp0 = cols2 + (size_t)(pxw + l16) * KK_ + quad * 8;
    const u16* bp1 = bp0 + 16 * KK_;
    const u16* ap  = wA3 + (size_t)l16 * KK_ + quad * 8;

    for (int kc = 0; kc < KK_ / 32; ++kc) {      // 18 chunks of 32
        v8s bfr[2];
        bfr[0] = *(const v8s*)(bp0 + kc * 32);
        bfr[1] = *(const v8s*)(bp1 + kc * 32);
        v8s afr[4];
#pragma unroll
        for (int mh = 0; mh < 4; ++mh)
            afr[mh] = *(const v8s*)(ap + mh * 16 * KK_ + kc * 32);
#pragma unroll
        for (int mh = 0; mh < 4; ++mh)
#pragma unroll
            for (int nh = 0; nh < 2; ++nh)
                acc[mh][nh] = __builtin_amdgcn_mfma_f32_16x16x32_bf16(
                    afr[mh], bfr[nh], acc[mh][nh], 0, 0, 0);
    }

    // D layout (R4-verified): col = l16 (px), row = quad*4 + r (cout)
    float* outb = out + n * (COUT_ * HW_);
#pragma unroll
    for (int mh = 0; mh < 4; ++mh)
#pragma unroll
        for (int nh = 0; nh < 2; ++nh)
#pragma unroll
            for (int r = 0; r < 4; ++r) {
                const int m = mh * 16 + quad * 4 + r;
                outb[m * HW_ + hwb + nh * 16 + l16] = acc[mh][nh][r] + bias[m];
            }
}

// ---------------------------------------------------------------------------
// Fallback (ws too small): R3-style direct fp32 kernel, no ws needed.
// ---------------------------------------------------------------------------
__global__ __launch_bounds__(256) void dcn_fallback(
    const float* __restrict__ x, const float* __restrict__ offset,
    const float* __restrict__ mask, const float* __restrict__ wptr,
    const float* __restrict__ bias, float* __restrict__ out)
{
    const int pix = blockIdx.x * 256 + threadIdx.x;
    const int n = pix >> 14, hw = pix & (HW_ - 1);
    const int ho = hw >> 7,  wo = hw & (W_ - 1);
    float acc[COUT_];
#pragma unroll
    for (int o = 0; o < COUT_; ++o) acc[o] = bias[o];
    const float* xn   = x + n * (C_ * HW_);
    const float* offn = offset + n * (2 * K_ * HW_) + hw;
    const float* mn   = mask + n * (K_ * HW_) + hw;
    for (int ct = 0; ct < C_; ct += 8) {
        for (int k = 0; k < K_; ++k) {
            const int ky = k / KW_, kx = k - ky * KW_;
            const float off_y = offn[(2 * k + 0) * HW_];
            const float off_x = offn[(2 * k + 1) * HW_];
            const float m = mn[k * HW_];
            const float py = (float)(ho - 1 + ky) + off_y;
            const float px = (float)(wo - 1 + kx) + off_x;
            const float y0f = floorf(py), x0f = floorf(px);
            const float ly = py - y0f, lx = px - x0f;
            const int y0 = (int)y0f, x0 = (int)x0f, y1 = y0 + 1, x1 = x0 + 1;
            const bool vy0 = (y0 >= 0) & (y0 < H_), vy1 = (y1 >= 0) & (y1 < H_);
            const bool vx0 = (x0 >= 0) & (x0 < W_), vx1 = (x1 >= 0) & (x1 < W_);
            const int cy0 = min(max(y0, 0), H_ - 1), cy1 = min(max(y1, 0), H_ - 1);
            const int cx0 = min(max(x0, 0), W_ - 1), cx1 = min(max(x1, 0), W_ - 1);
            const int i00 = cy0 * W_ + cx0, i01 = cy0 * W_ + cx1;
            const int i10 = cy1 * W_ + cx0, i11 = cy1 * W_ + cx1;
            const float f00 = (1.f - ly) * (1.f - lx) * m * ((vy0 && vx0) ? 1.f : 0.f);
            const float f01 = (1.f - ly) * lx * m * ((vy0 && vx1) ? 1.f : 0.f);
            const float f10 = ly * (1.f - lx) * m * ((vy1 && vx0) ? 1.f : 0.f);
            const float f11 = ly * lx * m * ((vy1 && vx1) ? 1.f : 0.f);
            for (int cc = 0; cc < 8; ++cc) {
                const int c = ct + cc;
                const float* xc = xn + c * HW_;
                const float val = fmaf(f00, xc[i00], fmaf(f01, xc[i01],
                                  fmaf(f10, xc[i10], f11 * xc[i11])));
#pragma unroll
                for (int o = 0; o < COUT_; ++o)
                    acc[o] = fmaf(wptr[o * (C_ * K_) + c * K_ + k], val, acc[o]);
            }
        }
    }
    float* outp = out + n * (COUT_ * HW_) + hw;
#pragma unroll
    for (int o = 0; o < COUT_; ++o) outp[o * HW_] = acc[o];
}

extern "C" void kernel_launch(void* const* d_in, const int* in_sizes, int n_in,
                              void* d_out, int out_size, void* d_ws, size_t ws_size,
                              hipStream_t stream) {
    const float* x      = (const float*)d_in[0];
    const float* offset = (const float*)d_in[1];
    const float* mask   = (const float*)d_in[2];
    const float* weight = (const float*)d_in[3];
    const float* bias   = (const float*)d_in[4];
    float* out = (float*)d_out;

    const size_t cols_bytes = (size_t)NPIX * KK_ * sizeof(u16);      // 75.5 MB
    const size_t xh_bytes   = (size_t)NPIX * C_ * sizeof(float);     // 16.8 MB
    const size_t wA_bytes   = (size_t)COUT_ * KK_ * sizeof(u16);     // 73.7 KB

    if (ws_size >= cols_bytes + xh_bytes + wA_bytes) {
        u16*   cols2 = (u16*)d_ws;
        float* xh    = (float*)((char*)d_ws + cols_bytes);
        u16*   wA3   = (u16*)((char*)d_ws + cols_bytes + xh_bytes);
        build_wA<<<(COUT_ * KK_ + 255) / 256, 256, 0, stream>>>(weight, wA3);
        transpose_x<<<N_ * 256, 256, 0, stream>>>(x, xh);
        im2col<<<NPIX / 32, 256, 0, stream>>>(xh, offset, mask, cols2);
        gemm_mfma<<<NPIX / 128, 256, 0, stream>>>(cols2, wA3, bias, out);
    } else {
        dcn_fallback<<<NPIX / 256, 256, 0, stream>>>(x, offset, mask, weight, bias, out);
    }
}